// Round 14
// baseline (520.269 us; speedup 1.0000x reference)
//
#include <hip/hip_runtime.h>

// ---------------- bf16 helpers ----------------
__device__ __forceinline__ unsigned short f2bf(float f) {
    union { float f; unsigned int u; } c; c.f = f;
    unsigned int r = c.u + 0x7fffu + ((c.u >> 16) & 1u);  // RTNE
    return (unsigned short)(r >> 16);
}
__device__ __forceinline__ float bflo(unsigned int v) {
    union { unsigned int u; float f; } c; c.u = v << 16; return c.f;
}
__device__ __forceinline__ float bfhi(unsigned int v) {
    union { unsigned int u; float f; } c; c.u = v & 0xffff0000u; return c.f;
}

// ---------------- CSR build ----------------
// Bins of 128 nodes by dst. Records pack (dst&127)<<20 | src (src < 2^20).
// k_binA: 256 blocks x 1024 threads, chunked two-phase; per-(block,bin) spans
// padded to 16 records (64B single-writer lines). Sentinel 0x7FFFFFFF
// (src-field >= N) skipped downstream.
// k_binC: per-(node,slice) cursors -> col is slice-sorted within each row;
// emits rowptrS[node*8+slice] for the slice-phased aggregation.

#define BIN_CAP 8192
#define NBINS_MAX 1024  // N=100000 -> 782 bins

__global__ __launch_bounds__(1024) void k_binA(const int* __restrict__ src,
                                               const int* __restrict__ dst,
                                               int* __restrict__ bincntPad,
                                               int* __restrict__ bincntExact,
                                               int* __restrict__ binbuf,
                                               int E, int nbins) {
    __shared__ int hist[NBINS_MAX];
    __shared__ int lbase[NBINS_MAX];
    int tid = threadIdx.x;
    int chunk = (E + gridDim.x - 1) / gridDim.x;
    int e0 = blockIdx.x * chunk;
    int e1 = min(e0 + chunk, E);

    for (int i = tid; i < nbins; i += 1024) hist[i] = 0;
    __syncthreads();
    for (int e = e0 + tid; e < e1; e += 1024) atomicAdd(&hist[dst[e] >> 7], 1);
    __syncthreads();
    for (int i = tid; i < nbins; i += 1024) {
        int c = hist[i];
        if (c) {
            atomicAdd(&bincntExact[i], c);
            lbase[i] = atomicAdd(&bincntPad[i], (c + 15) & ~15);
        }
        hist[i] = 0;  // reuse as cursor
    }
    __syncthreads();
    for (int e = e0 + tid; e < e1; e += 1024) {
        int d = dst[e], s = src[e];
        int b = d >> 7;
        int pos = lbase[b] + atomicAdd(&hist[b], 1);
        binbuf[(size_t)b * BIN_CAP + pos] = ((d & 127) << 20) | s;
    }
    __syncthreads();
    // sentinel-pad each span tail to the 16-record boundary
    for (int i = tid; i < nbins; i += 1024) {
        int c = hist[i];
        if (c & 15) {
            int* p = binbuf + (size_t)i * BIN_CAP + lbase[i] + c;
            int pad = 16 - (c & 15);
            for (int j = 0; j < pad; j++) p[j] = 0x7FFFFFFF;
        }
    }
}

// single-block exclusive scan of exact bin counts -> binstart (nbins <= 1024)
__global__ void k_scanB(const int* __restrict__ cntE, int* __restrict__ binstart,
                        int nbins) {
    __shared__ int s[1024];
    int tid = threadIdx.x;
    int v = (tid < nbins) ? cntE[tid] : 0;
    s[tid] = v;
    __syncthreads();
    for (int off = 1; off < 1024; off <<= 1) {
        int t = (tid >= off) ? s[tid - off] : 0;
        __syncthreads();
        s[tid] += t;
        __syncthreads();
    }
    if (tid < nbins) binstart[tid] = s[tid] - v;
}

// one block (1024 thr) per bin: pass1 histogram over (node,slice) -> dinv +
// rowptrS (coalesced); pass2 scatter col via per-(node,slice) LDS cursors so
// each row's col entries are grouped by src slice (slice = src>>14).
__global__ __launch_bounds__(1024) void k_binC(const int* __restrict__ bincntPad,
                                               const int* __restrict__ binstart,
                                               const int* __restrict__ binbuf,
                                               float* __restrict__ dinv,
                                               int* __restrict__ rowptrS,
                                               int* __restrict__ col, int n) {
    __shared__ int hist[1024];
    __shared__ int scn[1024];
    __shared__ int cur[1024];
    int b = blockIdx.x, tid = threadIdx.x;
    int cnt = bincntPad[b];  // multiple of 16
    const int* rec = binbuf + (size_t)b * BIN_CAP;
    hist[tid] = 0;
    __syncthreads();
    for (int i = tid * 4; i + 3 < cnt; i += 4096) {
        int4 r4 = *(const int4*)&rec[i];
        int s;
        s = r4.x & 0xFFFFF; if (s < n) atomicAdd(&hist[((r4.x >> 20) & 127) * 8 + (s >> 14)], 1);
        s = r4.y & 0xFFFFF; if (s < n) atomicAdd(&hist[((r4.y >> 20) & 127) * 8 + (s >> 14)], 1);
        s = r4.z & 0xFFFFF; if (s < n) atomicAdd(&hist[((r4.z >> 20) & 127) * 8 + (s >> 14)], 1);
        s = r4.w & 0xFFFFF; if (s < n) atomicAdd(&hist[((r4.w >> 20) & 127) * 8 + (s >> 14)], 1);
    }
    __syncthreads();
    int v = hist[tid];
    scn[tid] = v;
    __syncthreads();
    for (int off = 1; off < 1024; off <<= 1) {
        int t = (tid >= off) ? scn[tid - off] : 0;
        __syncthreads();
        scn[tid] += t;
        __syncthreads();
    }
    int rowbase = binstart[b];
    int excl = rowbase + scn[tid] - v;
    cur[tid] = excl;
    rowptrS[(size_t)b * 1024 + tid] = excl;
    if (tid < 128) {
        int node = b * 128 + tid;
        if (node < n) {
            int deg = 0;
#pragma unroll
            for (int k2 = 0; k2 < 8; k2++) deg += hist[tid * 8 + k2];
            dinv[node] = rsqrtf((float)(deg + 1));  // +1 self loop
        }
    }
    __syncthreads();
    for (int i = tid * 4; i + 3 < cnt; i += 4096) {
        int4 r4 = *(const int4*)&rec[i];
        int s;
        s = r4.x & 0xFFFFF; if (s < n) col[atomicAdd(&cur[((r4.x >> 20) & 127) * 8 + (s >> 14)], 1)] = s;
        s = r4.y & 0xFFFFF; if (s < n) col[atomicAdd(&cur[((r4.y >> 20) & 127) * 8 + (s >> 14)], 1)] = s;
        s = r4.z & 0xFFFFF; if (s < n) col[atomicAdd(&cur[((r4.z >> 20) & 127) * 8 + (s >> 14)], 1)] = s;
        s = r4.w & 0xFFFFF; if (s < n) col[atomicAdd(&cur[((r4.w >> 20) & 127) * 8 + (s >> 14)], 1)] = s;
    }
}

// ---------------- dense compute (h, u stored as bf16) ----------------

// layer-0 fused: h = x @ emb_w^T + emb_b computed in-LDS, then u = (h @ W^T)*dinv -> bf16
__global__ __launch_bounds__(256) void k_gemm0(const float* __restrict__ x,
                                               const float* __restrict__ embw,
                                               const float* __restrict__ embb,
                                               const float* __restrict__ W,
                                               const float* __restrict__ dinv,
                                               unsigned short* __restrict__ uout, int n) {
    __shared__ float hN[64 * 68];
    __shared__ float wT[64 * 68];
    __shared__ float sX[64 * 4];
    __shared__ float sW[64 * 4];
    __shared__ float sB[64];
    int tid = threadIdx.x;
    int nbase = blockIdx.x * 64;
    for (int i = tid; i < 4096; i += 256) {
        int j = i >> 6, k = i & 63;
        wT[k * 68 + j] = W[i];
    }
    if (tid < 256) sW[tid] = embw[tid];
    if (tid < 64) sB[tid] = embb[tid];
    {
        int node = nbase + (tid >> 2);
        sX[tid] = (node < n) ? x[(size_t)node * 4 + (tid & 3)] : 0.f;
    }
    __syncthreads();
    for (int i = tid; i < 4096; i += 256) {
        int nn = i >> 6, k = i & 63;
        float s = sB[k];
        s = fmaf(sX[nn * 4 + 0], sW[k * 4 + 0], s);
        s = fmaf(sX[nn * 4 + 1], sW[k * 4 + 1], s);
        s = fmaf(sX[nn * 4 + 2], sW[k * 4 + 2], s);
        s = fmaf(sX[nn * 4 + 3], sW[k * 4 + 3], s);
        hN[nn * 68 + k] = s;
    }
    __syncthreads();

    int tx = tid & 15;
    int ty = tid >> 4;
    float acc[4][4] = {};
#pragma unroll
    for (int k0 = 0; k0 < 64; k0 += 4) {
        float a[4][4], w[4][4];
#pragma unroll
        for (int i = 0; i < 4; i++)
            *(float4*)a[i] = *(const float4*)&hN[(ty * 4 + i) * 68 + k0];
#pragma unroll
        for (int dk = 0; dk < 4; dk++)
            *(float4*)w[dk] = *(const float4*)&wT[(k0 + dk) * 68 + tx * 4];
#pragma unroll
        for (int i = 0; i < 4; i++)
#pragma unroll
            for (int j = 0; j < 4; j++)
#pragma unroll
                for (int dk = 0; dk < 4; dk++)
                    acc[i][j] = fmaf(a[i][dk], w[dk][j], acc[i][j]);
    }
#pragma unroll
    for (int i = 0; i < 4; i++) {
        int node = nbase + ty * 4 + i;
        if (node < n) {
            float sc = dinv[node];
            ushort4 o;
            o.x = f2bf(acc[i][0] * sc);
            o.y = f2bf(acc[i][1] * sc);
            o.z = f2bf(acc[i][2] * sc);
            o.w = f2bf(acc[i][3] * sc);
            *(ushort4*)&uout[(size_t)node * 64 + tx * 4] = o;
        }
    }
}

// u = (h @ W^T) * dinv[node]; h bf16 in, u bf16 out
__global__ __launch_bounds__(256) void k_gemm(const unsigned short* __restrict__ hin,
                                              const float* __restrict__ W,
                                              const float* __restrict__ dinv,
                                              unsigned short* __restrict__ uout, int n) {
    __shared__ float hN[64 * 68];
    __shared__ float wT[64 * 68];
    int tid = threadIdx.x;
    int nbase = blockIdx.x * 64;
    for (int i = tid; i < 4096; i += 256) {
        int j = i >> 6, k = i & 63;
        wT[k * 68 + j] = W[i];
    }
    for (int i = tid; i < 2048; i += 256) {
        int nn = i >> 5, k2 = i & 31;
        int node = nbase + nn;
        unsigned int v = (node < n) ? ((const unsigned int*)hin)[(size_t)node * 32 + k2] : 0u;
        hN[nn * 68 + k2 * 2 + 0] = bflo(v);
        hN[nn * 68 + k2 * 2 + 1] = bfhi(v);
    }
    __syncthreads();

    int tx = tid & 15;
    int ty = tid >> 4;
    float acc[4][4] = {};
#pragma unroll
    for (int k0 = 0; k0 < 64; k0 += 4) {
        float a[4][4], w[4][4];
#pragma unroll
        for (int i = 0; i < 4; i++)
            *(float4*)a[i] = *(const float4*)&hN[(ty * 4 + i) * 68 + k0];
#pragma unroll
        for (int dk = 0; dk < 4; dk++)
            *(float4*)w[dk] = *(const float4*)&wT[(k0 + dk) * 68 + tx * 4];
#pragma unroll
        for (int i = 0; i < 4; i++)
#pragma unroll
            for (int j = 0; j < 4; j++)
#pragma unroll
                for (int dk = 0; dk < 4; dk++)
                    acc[i][j] = fmaf(a[i][dk], w[dk][j], acc[i][j]);
    }
#pragma unroll
    for (int i = 0; i < 4; i++) {
        int node = nbase + ty * 4 + i;
        if (node < n) {
            float sc = dinv[node];
            ushort4 o;
            o.x = f2bf(acc[i][0] * sc);
            o.y = f2bf(acc[i][1] * sc);
            o.z = f2bf(acc[i][2] * sc);
            o.w = f2bf(acc[i][3] * sc);
            *(ushort4*)&uout[(size_t)node * 64 + tx * 4] = o;
        }
    }
}

// slice-phased resident-grid aggregation: 1250 blocks (all co-resident),
// each wave owns 20 nodes (group g owns nodes i*4+g, acc in registers).
// Outer loop over 8 src-slices: all waves read the same 2 MB u-window per
// phase -> per-XCD L2 resident -> near cold-miss-only traffic.
// h[n] = relu(dinv[n] * (u[n] + sum_in u[s]) + bias)
#define NPB 80  // nodes per block (4 waves x 20)
__global__ __launch_bounds__(256) void k_agg(const unsigned short* __restrict__ u,
                                             const int* __restrict__ rowptrS,
                                             const int* __restrict__ col,
                                             const float* __restrict__ dinv,
                                             const float* __restrict__ bias,
                                             unsigned short* __restrict__ hout, int n) {
    int tid = threadIdx.x;
    int wave = tid >> 6, lane = tid & 63;
    int g = lane >> 4, t = lane & 15;
    int gb = g << 4;
    int wbase = blockIdx.x * NPB + wave * (NPB / 4);
    const unsigned int* u32 = (const unsigned int*)u;
    const int toff = t * 2;

    float acc[5][4] = {};
    int segp[5];
#pragma unroll
    for (int i = 0; i < 5; i++) {
        int node = wbase + i * 4 + g;
        segp[i] = (node < n) ? rowptrS[node * 8] : 0;
    }
#pragma unroll 1
    for (int sl = 0; sl < 8; sl++) {
#pragma unroll
        for (int i = 0; i < 5; i++) {
            int node = wbase + i * 4 + g;
            if (node >= n) continue;
            int pend = rowptrS[node * 8 + sl + 1];
            int p = segp[i];
            segp[i] = pend;
            while (p < pend) {
                int m = min(pend - p, 16);
                int cv = (t < m) ? col[p + t] : 0;
                int e = 0;
                for (; e + 3 < m; e += 4) {
                    int s0 = __shfl(cv, gb + e + 0, 64);
                    int s1 = __shfl(cv, gb + e + 1, 64);
                    int s2 = __shfl(cv, gb + e + 2, 64);
                    int s3 = __shfl(cv, gb + e + 3, 64);
                    uint2 v0 = *(const uint2*)&u32[(size_t)s0 * 32 + toff];
                    uint2 v1 = *(const uint2*)&u32[(size_t)s1 * 32 + toff];
                    uint2 v2 = *(const uint2*)&u32[(size_t)s2 * 32 + toff];
                    uint2 v3 = *(const uint2*)&u32[(size_t)s3 * 32 + toff];
                    acc[i][0] += bflo(v0.x); acc[i][1] += bfhi(v0.x);
                    acc[i][2] += bflo(v0.y); acc[i][3] += bfhi(v0.y);
                    acc[i][0] += bflo(v1.x); acc[i][1] += bfhi(v1.x);
                    acc[i][2] += bflo(v1.y); acc[i][3] += bfhi(v1.y);
                    acc[i][0] += bflo(v2.x); acc[i][1] += bfhi(v2.x);
                    acc[i][2] += bflo(v2.y); acc[i][3] += bfhi(v2.y);
                    acc[i][0] += bflo(v3.x); acc[i][1] += bfhi(v3.x);
                    acc[i][2] += bflo(v3.y); acc[i][3] += bfhi(v3.y);
                }
                for (; e < m; e++) {
                    int s0 = __shfl(cv, gb + e, 64);
                    uint2 v0 = *(const uint2*)&u32[(size_t)s0 * 32 + toff];
                    acc[i][0] += bflo(v0.x); acc[i][1] += bfhi(v0.x);
                    acc[i][2] += bflo(v0.y); acc[i][3] += bfhi(v0.y);
                }
                p += m;
            }
        }
    }
    // epilogue: self-loop + dinv scale + bias + relu -> bf16
#pragma unroll
    for (int i = 0; i < 5; i++) {
        int node = wbase + i * 4 + g;
        if (node < n) {
            uint2 sv = *(const uint2*)&u32[(size_t)node * 32 + toff];
            float sc = dinv[node];
            float f0 = fmaxf(fmaf(sc, acc[i][0] + bflo(sv.x), bias[t * 4 + 0]), 0.f);
            float f1 = fmaxf(fmaf(sc, acc[i][1] + bfhi(sv.x), bias[t * 4 + 1]), 0.f);
            float f2 = fmaxf(fmaf(sc, acc[i][2] + bflo(sv.y), bias[t * 4 + 2]), 0.f);
            float f3 = fmaxf(fmaf(sc, acc[i][3] + bfhi(sv.y), bias[t * 4 + 3]), 0.f);
            ushort4 o;
            o.x = f2bf(f0); o.y = f2bf(f1); o.z = f2bf(f2); o.w = f2bf(f3);
            *(ushort4*)&hout[(size_t)node * 64 + t * 4] = o;
        }
    }
}

// one wave per graph: mean pool (contiguous rows, 16-lane groups x uint2) + MLP head
__global__ __launch_bounds__(256) void k_pool(const unsigned short* __restrict__ h,
                                              const int* __restrict__ batch,
                                              const float* __restrict__ l1w,
                                              const float* __restrict__ l1b,
                                              const float* __restrict__ l2w,
                                              const float* __restrict__ l2b,
                                              float* __restrict__ out, int n, int G) {
    __shared__ float wl[64 * 65];
    __shared__ float gsm[4][64];
    int tid = threadIdx.x;
    for (int i = tid; i < 4096; i += 256) {
        int j = i >> 6, k = i & 63;
        wl[j * 65 + k] = l1w[i];
    }
    int wv = tid >> 6;
    int lane = tid & 63;
    int g = blockIdx.x * 4 + wv;
    int grp = lane >> 4, t = lane & 15;
    const unsigned int* h32 = (const unsigned int*)h;

    int start = 0, end = 0;
    if (g < G) {
        int lo = 0, hi = n;
        while (lo < hi) { int mid = (lo + hi) >> 1; if (batch[mid] < g) lo = mid + 1; else hi = mid; }
        start = lo;
        hi = n;
        while (lo < hi) { int mid = (lo + hi) >> 1; if (batch[mid] < g + 1) lo = mid + 1; else hi = mid; }
        end = lo;
    }

    float a0 = 0.f, a1 = 0.f, a2 = 0.f, a3 = 0.f;
    int nb = start;
    for (; nb + 4 <= end; nb += 4) {
        int node = nb + grp;
        uint2 v = *(const uint2*)&h32[(size_t)node * 32 + t * 2];
        a0 += bflo(v.x); a1 += bfhi(v.x); a2 += bflo(v.y); a3 += bfhi(v.y);
    }
    if (grp < end - nb) {
        int node = nb + grp;
        uint2 v = *(const uint2*)&h32[(size_t)node * 32 + t * 2];
        a0 += bflo(v.x); a1 += bfhi(v.x); a2 += bflo(v.y); a3 += bfhi(v.y);
    }
    a0 += __shfl_xor(a0, 16, 64); a1 += __shfl_xor(a1, 16, 64);
    a2 += __shfl_xor(a2, 16, 64); a3 += __shfl_xor(a3, 16, 64);
    a0 += __shfl_xor(a0, 32, 64); a1 += __shfl_xor(a1, 32, 64);
    a2 += __shfl_xor(a2, 32, 64); a3 += __shfl_xor(a3, 32, 64);

    float cnt = (float)((end - start) > 0 ? (end - start) : 1);
    if (grp == 0) {
        gsm[wv][t * 4 + 0] = a0 / cnt;
        gsm[wv][t * 4 + 1] = a1 / cnt;
        gsm[wv][t * 4 + 2] = a2 / cnt;
        gsm[wv][t * 4 + 3] = a3 / cnt;
    }
    __syncthreads();
    if (g < G) {
        float pj = l1b[lane];
#pragma unroll
        for (int k = 0; k < 64; k++) pj = fmaf(gsm[wv][k], wl[lane * 65 + k], pj);
        pj = fmaxf(pj, 0.f);
        for (int o = 0; o < 3; o++) {
            float v = pj * l2w[o * 64 + lane];
            for (int off = 32; off; off >>= 1) v += __shfl_xor(v, off, 64);
            if (lane == 0) out[g * 3 + o] = v + l2b[o];
        }
    }
}

// ---------------- launch ----------------

extern "C" void kernel_launch(void* const* d_in, const int* in_sizes, int n_in,
                              void* d_out, int out_size, void* d_ws, size_t ws_size,
                              hipStream_t stream) {
    const float* x      = (const float*)d_in[0];
    const int*   edge   = (const int*)d_in[1];
    const int*   batch  = (const int*)d_in[2];
    const float* emb_w  = (const float*)d_in[3];
    const float* emb_b  = (const float*)d_in[4];
    const float* conv_w = (const float*)d_in[5];
    const float* conv_b = (const float*)d_in[6];
    const float* l1w    = (const float*)d_in[7];
    const float* l1b    = (const float*)d_in[8];
    const float* l2w    = (const float*)d_in[9];
    const float* l2b    = (const float*)d_in[10];
    float* out = (float*)d_out;

    const int N = in_sizes[2];      // 100000 nodes
    const int E = in_sizes[1] / 2;  // 3200000 edges
    const int G = out_size / 3;     // 2000 graphs
    const int NB = (N + 127) >> 7;  // bins of 128 nodes (782)

    char* ws = (char*)d_ws;
    size_t off = 0;
    auto alloc = [&](size_t bytes) -> void* {
        void* p = ws + off;
        off = (off + bytes + 255) & ~(size_t)255;
        return p;
    };
    float* dinv     = (float*)alloc((size_t)N * 4);
    int*   bincntP  = (int*)alloc((size_t)NB * 4);
    int*   bincntE  = (int*)alloc((size_t)NB * 4);
    int*   binstart = (int*)alloc((size_t)NB * 4);
    int*   colw     = (int*)alloc((size_t)E * 4);
    int*   rowptrS  = (int*)alloc(((size_t)NB * 1024 + 8) * 4);  // 3.2 MB
    int*   binbuf   = (int*)alloc((size_t)NB * BIN_CAP * 4);     // 25.6 MB
    // ubuf/hbuf alias binbuf (dead after k_binC):
    //   ubuf = binbuf[0 .. 12.8MB), first written by k_gemm0
    //   hbuf = binbuf[12.8MB .. 25.6MB), first written by first k_agg
    unsigned short* ubuf = (unsigned short*)binbuf;
    unsigned short* hbuf = (unsigned short*)((char*)binbuf + (size_t)N * 64 * 2);

    const int* esrc = edge;
    const int* edst = edge + E;

    // bincntP and bincntE are adjacent in ws -> one memset covers both
    hipMemsetAsync(bincntP, 0, (size_t)((char*)bincntE - (char*)bincntP) + (size_t)NB * 4, stream);
    k_binA<<<256, 1024, 0, stream>>>(esrc, edst, bincntP, bincntE, binbuf, E, NB);
    k_scanB<<<1, 1024, 0, stream>>>(bincntE, binstart, NB);
    k_binC<<<NB, 1024, 0, stream>>>(bincntP, binstart, binbuf, dinv, rowptrS, colw, N);

    int aggBlocks = (N + NPB - 1) / NPB;  // 1250 -> all co-resident (~5/CU)
    k_gemm0<<<(N + 63) / 64, 256, 0, stream>>>(x, emb_w, emb_b, conv_w, dinv, ubuf, N);
    k_agg<<<aggBlocks, 256, 0, stream>>>(ubuf, rowptrS, colw, dinv, conv_b, hbuf, N);
    for (int l = 1; l < 3; l++) {
        k_gemm<<<(N + 63) / 64, 256, 0, stream>>>(hbuf, conv_w + (size_t)l * 64 * 64, dinv, ubuf, N);
        k_agg<<<aggBlocks, 256, 0, stream>>>(ubuf, rowptrS, colw, dinv,
                                             conv_b + (size_t)l * 64, hbuf, N);
    }

    k_pool<<<(G + 3) / 4, 256, 0, stream>>>(hbuf, batch, l1w, l1b, l2w, l2b, out, N, G);
}

// Round 15
// 472.857 us; speedup vs baseline: 1.1003x; 1.1003x over previous
//
#include <hip/hip_runtime.h>

// ---------------- bf16 helpers ----------------
__device__ __forceinline__ unsigned short f2bf(float f) {
    union { float f; unsigned int u; } c; c.f = f;
    unsigned int r = c.u + 0x7fffu + ((c.u >> 16) & 1u);  // RTNE
    return (unsigned short)(r >> 16);
}
__device__ __forceinline__ float bflo(unsigned int v) {
    union { unsigned int u; float f; } c; c.u = v << 16; return c.f;
}
__device__ __forceinline__ float bfhi(unsigned int v) {
    union { unsigned int u; float f; } c; c.u = v & 0xffff0000u; return c.f;
}

// ---------------- CSR build ----------------
// Bins of 128 nodes by dst. Records pack (dst&127)<<20 | src (src < 2^20).
// k_binA: 256 blocks x 1024 threads, chunked two-phase; per-(block,bin) spans
// padded to 16 records (64B single-writer lines). Sentinel 0x7FFFFFFF
// (src-field >= N) skipped downstream.
// k_binC: per-(node,slice) cursors -> col is slice-sorted within each row;
// emits rowptrS[node*8+slice] (slice = src>>14). k_agg consumes PAIRS of
// slices (4 super-slices of 3.2 MB each).

#define BIN_CAP 8192
#define NBINS_MAX 1024  // N=100000 -> 782 bins

__global__ __launch_bounds__(1024) void k_binA(const int* __restrict__ src,
                                               const int* __restrict__ dst,
                                               int* __restrict__ bincntPad,
                                               int* __restrict__ bincntExact,
                                               int* __restrict__ binbuf,
                                               int E, int nbins) {
    __shared__ int hist[NBINS_MAX];
    __shared__ int lbase[NBINS_MAX];
    int tid = threadIdx.x;
    int chunk = (E + gridDim.x - 1) / gridDim.x;
    int e0 = blockIdx.x * chunk;
    int e1 = min(e0 + chunk, E);

    for (int i = tid; i < nbins; i += 1024) hist[i] = 0;
    __syncthreads();
    for (int e = e0 + tid; e < e1; e += 1024) atomicAdd(&hist[dst[e] >> 7], 1);
    __syncthreads();
    for (int i = tid; i < nbins; i += 1024) {
        int c = hist[i];
        if (c) {
            atomicAdd(&bincntExact[i], c);
            lbase[i] = atomicAdd(&bincntPad[i], (c + 15) & ~15);
        }
        hist[i] = 0;  // reuse as cursor
    }
    __syncthreads();
    for (int e = e0 + tid; e < e1; e += 1024) {
        int d = dst[e], s = src[e];
        int b = d >> 7;
        int pos = lbase[b] + atomicAdd(&hist[b], 1);
        binbuf[(size_t)b * BIN_CAP + pos] = ((d & 127) << 20) | s;
    }
    __syncthreads();
    // sentinel-pad each span tail to the 16-record boundary
    for (int i = tid; i < nbins; i += 1024) {
        int c = hist[i];
        if (c & 15) {
            int* p = binbuf + (size_t)i * BIN_CAP + lbase[i] + c;
            int pad = 16 - (c & 15);
            for (int j = 0; j < pad; j++) p[j] = 0x7FFFFFFF;
        }
    }
}

// single-block exclusive scan of exact bin counts -> binstart (nbins <= 1024)
__global__ void k_scanB(const int* __restrict__ cntE, int* __restrict__ binstart,
                        int nbins) {
    __shared__ int s[1024];
    int tid = threadIdx.x;
    int v = (tid < nbins) ? cntE[tid] : 0;
    s[tid] = v;
    __syncthreads();
    for (int off = 1; off < 1024; off <<= 1) {
        int t = (tid >= off) ? s[tid - off] : 0;
        __syncthreads();
        s[tid] += t;
        __syncthreads();
    }
    if (tid < nbins) binstart[tid] = s[tid] - v;
}

// one block (1024 thr) per bin: pass1 histogram over (node,slice) -> dinv +
// rowptrS (coalesced); pass2 scatter col via per-(node,slice) LDS cursors so
// each row's col entries are grouped by src slice (slice = src>>14).
__global__ __launch_bounds__(1024) void k_binC(const int* __restrict__ bincntPad,
                                               const int* __restrict__ binstart,
                                               const int* __restrict__ binbuf,
                                               float* __restrict__ dinv,
                                               int* __restrict__ rowptrS,
                                               int* __restrict__ col, int n) {
    __shared__ int hist[1024];
    __shared__ int scn[1024];
    __shared__ int cur[1024];
    int b = blockIdx.x, tid = threadIdx.x;
    int cnt = bincntPad[b];  // multiple of 16
    const int* rec = binbuf + (size_t)b * BIN_CAP;
    hist[tid] = 0;
    __syncthreads();
    for (int i = tid * 4; i + 3 < cnt; i += 4096) {
        int4 r4 = *(const int4*)&rec[i];
        int s;
        s = r4.x & 0xFFFFF; if (s < n) atomicAdd(&hist[((r4.x >> 20) & 127) * 8 + (s >> 14)], 1);
        s = r4.y & 0xFFFFF; if (s < n) atomicAdd(&hist[((r4.y >> 20) & 127) * 8 + (s >> 14)], 1);
        s = r4.z & 0xFFFFF; if (s < n) atomicAdd(&hist[((r4.z >> 20) & 127) * 8 + (s >> 14)], 1);
        s = r4.w & 0xFFFFF; if (s < n) atomicAdd(&hist[((r4.w >> 20) & 127) * 8 + (s >> 14)], 1);
    }
    __syncthreads();
    int v = hist[tid];
    scn[tid] = v;
    __syncthreads();
    for (int off = 1; off < 1024; off <<= 1) {
        int t = (tid >= off) ? scn[tid - off] : 0;
        __syncthreads();
        scn[tid] += t;
        __syncthreads();
    }
    int rowbase = binstart[b];
    int excl = rowbase + scn[tid] - v;
    cur[tid] = excl;
    rowptrS[(size_t)b * 1024 + tid] = excl;
    if (tid < 128) {
        int node = b * 128 + tid;
        if (node < n) {
            int deg = 0;
#pragma unroll
            for (int k2 = 0; k2 < 8; k2++) deg += hist[tid * 8 + k2];
            dinv[node] = rsqrtf((float)(deg + 1));  // +1 self loop
        }
    }
    __syncthreads();
    for (int i = tid * 4; i + 3 < cnt; i += 4096) {
        int4 r4 = *(const int4*)&rec[i];
        int s;
        s = r4.x & 0xFFFFF; if (s < n) col[atomicAdd(&cur[((r4.x >> 20) & 127) * 8 + (s >> 14)], 1)] = s;
        s = r4.y & 0xFFFFF; if (s < n) col[atomicAdd(&cur[((r4.y >> 20) & 127) * 8 + (s >> 14)], 1)] = s;
        s = r4.z & 0xFFFFF; if (s < n) col[atomicAdd(&cur[((r4.z >> 20) & 127) * 8 + (s >> 14)], 1)] = s;
        s = r4.w & 0xFFFFF; if (s < n) col[atomicAdd(&cur[((r4.w >> 20) & 127) * 8 + (s >> 14)], 1)] = s;
    }
}

// ---------------- dense compute (h, u stored as bf16) ----------------

// layer-0 fused: h = x @ emb_w^T + emb_b computed in-LDS, then u = (h @ W^T)*dinv -> bf16
__global__ __launch_bounds__(256) void k_gemm0(const float* __restrict__ x,
                                               const float* __restrict__ embw,
                                               const float* __restrict__ embb,
                                               const float* __restrict__ W,
                                               const float* __restrict__ dinv,
                                               unsigned short* __restrict__ uout, int n) {
    __shared__ float hN[64 * 68];
    __shared__ float wT[64 * 68];
    __shared__ float sX[64 * 4];
    __shared__ float sW[64 * 4];
    __shared__ float sB[64];
    int tid = threadIdx.x;
    int nbase = blockIdx.x * 64;
    for (int i = tid; i < 4096; i += 256) {
        int j = i >> 6, k = i & 63;
        wT[k * 68 + j] = W[i];
    }
    if (tid < 256) sW[tid] = embw[tid];
    if (tid < 64) sB[tid] = embb[tid];
    {
        int node = nbase + (tid >> 2);
        sX[tid] = (node < n) ? x[(size_t)node * 4 + (tid & 3)] : 0.f;
    }
    __syncthreads();
    for (int i = tid; i < 4096; i += 256) {
        int nn = i >> 6, k = i & 63;
        float s = sB[k];
        s = fmaf(sX[nn * 4 + 0], sW[k * 4 + 0], s);
        s = fmaf(sX[nn * 4 + 1], sW[k * 4 + 1], s);
        s = fmaf(sX[nn * 4 + 2], sW[k * 4 + 2], s);
        s = fmaf(sX[nn * 4 + 3], sW[k * 4 + 3], s);
        hN[nn * 68 + k] = s;
    }
    __syncthreads();

    int tx = tid & 15;
    int ty = tid >> 4;
    float acc[4][4] = {};
#pragma unroll
    for (int k0 = 0; k0 < 64; k0 += 4) {
        float a[4][4], w[4][4];
#pragma unroll
        for (int i = 0; i < 4; i++)
            *(float4*)a[i] = *(const float4*)&hN[(ty * 4 + i) * 68 + k0];
#pragma unroll
        for (int dk = 0; dk < 4; dk++)
            *(float4*)w[dk] = *(const float4*)&wT[(k0 + dk) * 68 + tx * 4];
#pragma unroll
        for (int i = 0; i < 4; i++)
#pragma unroll
            for (int j = 0; j < 4; j++)
#pragma unroll
                for (int dk = 0; dk < 4; dk++)
                    acc[i][j] = fmaf(a[i][dk], w[dk][j], acc[i][j]);
    }
#pragma unroll
    for (int i = 0; i < 4; i++) {
        int node = nbase + ty * 4 + i;
        if (node < n) {
            float sc = dinv[node];
            ushort4 o;
            o.x = f2bf(acc[i][0] * sc);
            o.y = f2bf(acc[i][1] * sc);
            o.z = f2bf(acc[i][2] * sc);
            o.w = f2bf(acc[i][3] * sc);
            *(ushort4*)&uout[(size_t)node * 64 + tx * 4] = o;
        }
    }
}

// u = (h @ W^T) * dinv[node]; h bf16 in, u bf16 out
__global__ __launch_bounds__(256) void k_gemm(const unsigned short* __restrict__ hin,
                                              const float* __restrict__ W,
                                              const float* __restrict__ dinv,
                                              unsigned short* __restrict__ uout, int n) {
    __shared__ float hN[64 * 68];
    __shared__ float wT[64 * 68];
    int tid = threadIdx.x;
    int nbase = blockIdx.x * 64;
    for (int i = tid; i < 4096; i += 256) {
        int j = i >> 6, k = i & 63;
        wT[k * 68 + j] = W[i];
    }
    for (int i = tid; i < 2048; i += 256) {
        int nn = i >> 5, k2 = i & 31;
        int node = nbase + nn;
        unsigned int v = (node < n) ? ((const unsigned int*)hin)[(size_t)node * 32 + k2] : 0u;
        hN[nn * 68 + k2 * 2 + 0] = bflo(v);
        hN[nn * 68 + k2 * 2 + 1] = bfhi(v);
    }
    __syncthreads();

    int tx = tid & 15;
    int ty = tid >> 4;
    float acc[4][4] = {};
#pragma unroll
    for (int k0 = 0; k0 < 64; k0 += 4) {
        float a[4][4], w[4][4];
#pragma unroll
        for (int i = 0; i < 4; i++)
            *(float4*)a[i] = *(const float4*)&hN[(ty * 4 + i) * 68 + k0];
#pragma unroll
        for (int dk = 0; dk < 4; dk++)
            *(float4*)w[dk] = *(const float4*)&wT[(k0 + dk) * 68 + tx * 4];
#pragma unroll
        for (int i = 0; i < 4; i++)
#pragma unroll
            for (int j = 0; j < 4; j++)
#pragma unroll
                for (int dk = 0; dk < 4; dk++)
                    acc[i][j] = fmaf(a[i][dk], w[dk][j], acc[i][j]);
    }
#pragma unroll
    for (int i = 0; i < 4; i++) {
        int node = nbase + ty * 4 + i;
        if (node < n) {
            float sc = dinv[node];
            ushort4 o;
            o.x = f2bf(acc[i][0] * sc);
            o.y = f2bf(acc[i][1] * sc);
            o.z = f2bf(acc[i][2] * sc);
            o.w = f2bf(acc[i][3] * sc);
            *(ushort4*)&uout[(size_t)node * 64 + tx * 4] = o;
        }
    }
}

// slice-phased resident-grid aggregation, v2: 2084 blocks (~8/CU, near-full
// occupancy), each wave owns 12 nodes (group g owns nodes i*4+g, acc in
// registers). 4 super-slices of 3.2 MB (pairs of binC's 8 slices) -> ~8-edge
// segments -> ~8 gathers in flight per group, 32 per wave.
// h[n] = relu(dinv[n] * (u[n] + sum_in u[s]) + bias)
#define NPB 48  // nodes per block (4 waves x 12)
__global__ __launch_bounds__(256) void k_agg(const unsigned short* __restrict__ u,
                                             const int* __restrict__ rowptrS,
                                             const int* __restrict__ col,
                                             const float* __restrict__ dinv,
                                             const float* __restrict__ bias,
                                             unsigned short* __restrict__ hout, int n) {
    int tid = threadIdx.x;
    int wave = tid >> 6, lane = tid & 63;
    int g = lane >> 4, t = lane & 15;
    int gb = g << 4;
    int wbase = blockIdx.x * NPB + wave * (NPB / 4);
    const unsigned int* u32 = (const unsigned int*)u;
    const int toff = t * 2;

    float acc[3][4] = {};
    int segp[3];
#pragma unroll
    for (int i = 0; i < 3; i++) {
        int node = wbase + i * 4 + g;
        segp[i] = (node < n) ? rowptrS[node * 8] : 0;
    }
#pragma unroll 1
    for (int sl = 0; sl < 4; sl++) {
#pragma unroll
        for (int i = 0; i < 3; i++) {
            int node = wbase + i * 4 + g;
            if (node >= n) continue;
            int pend = rowptrS[node * 8 + sl * 2 + 2];
            int p = segp[i];
            segp[i] = pend;
            while (p < pend) {
                int m = min(pend - p, 16);
                int cv = (t < m) ? col[p + t] : 0;
                int e = 0;
                for (; e + 3 < m; e += 4) {
                    int s0 = __shfl(cv, gb + e + 0, 64);
                    int s1 = __shfl(cv, gb + e + 1, 64);
                    int s2 = __shfl(cv, gb + e + 2, 64);
                    int s3 = __shfl(cv, gb + e + 3, 64);
                    uint2 v0 = *(const uint2*)&u32[(size_t)s0 * 32 + toff];
                    uint2 v1 = *(const uint2*)&u32[(size_t)s1 * 32 + toff];
                    uint2 v2 = *(const uint2*)&u32[(size_t)s2 * 32 + toff];
                    uint2 v3 = *(const uint2*)&u32[(size_t)s3 * 32 + toff];
                    acc[i][0] += bflo(v0.x); acc[i][1] += bfhi(v0.x);
                    acc[i][2] += bflo(v0.y); acc[i][3] += bfhi(v0.y);
                    acc[i][0] += bflo(v1.x); acc[i][1] += bfhi(v1.x);
                    acc[i][2] += bflo(v1.y); acc[i][3] += bfhi(v1.y);
                    acc[i][0] += bflo(v2.x); acc[i][1] += bfhi(v2.x);
                    acc[i][2] += bflo(v2.y); acc[i][3] += bfhi(v2.y);
                    acc[i][0] += bflo(v3.x); acc[i][1] += bfhi(v3.x);
                    acc[i][2] += bflo(v3.y); acc[i][3] += bfhi(v3.y);
                }
                for (; e < m; e++) {
                    int s0 = __shfl(cv, gb + e, 64);
                    uint2 v0 = *(const uint2*)&u32[(size_t)s0 * 32 + toff];
                    acc[i][0] += bflo(v0.x); acc[i][1] += bfhi(v0.x);
                    acc[i][2] += bflo(v0.y); acc[i][3] += bfhi(v0.y);
                }
                p += m;
            }
        }
    }
    // epilogue: self-loop + dinv scale + bias + relu -> bf16
#pragma unroll
    for (int i = 0; i < 3; i++) {
        int node = wbase + i * 4 + g;
        if (node < n) {
            uint2 sv = *(const uint2*)&u32[(size_t)node * 32 + toff];
            float sc = dinv[node];
            float f0 = fmaxf(fmaf(sc, acc[i][0] + bflo(sv.x), bias[t * 4 + 0]), 0.f);
            float f1 = fmaxf(fmaf(sc, acc[i][1] + bfhi(sv.x), bias[t * 4 + 1]), 0.f);
            float f2 = fmaxf(fmaf(sc, acc[i][2] + bflo(sv.y), bias[t * 4 + 2]), 0.f);
            float f3 = fmaxf(fmaf(sc, acc[i][3] + bfhi(sv.y), bias[t * 4 + 3]), 0.f);
            ushort4 o;
            o.x = f2bf(f0); o.y = f2bf(f1); o.z = f2bf(f2); o.w = f2bf(f3);
            *(ushort4*)&hout[(size_t)node * 64 + t * 4] = o;
        }
    }
}

// one wave per graph: mean pool (contiguous rows, 16-lane groups x uint2) + MLP head
__global__ __launch_bounds__(256) void k_pool(const unsigned short* __restrict__ h,
                                              const int* __restrict__ batch,
                                              const float* __restrict__ l1w,
                                              const float* __restrict__ l1b,
                                              const float* __restrict__ l2w,
                                              const float* __restrict__ l2b,
                                              float* __restrict__ out, int n, int G) {
    __shared__ float wl[64 * 65];
    __shared__ float gsm[4][64];
    int tid = threadIdx.x;
    for (int i = tid; i < 4096; i += 256) {
        int j = i >> 6, k = i & 63;
        wl[j * 65 + k] = l1w[i];
    }
    int wv = tid >> 6;
    int lane = tid & 63;
    int g = blockIdx.x * 4 + wv;
    int grp = lane >> 4, t = lane & 15;
    const unsigned int* h32 = (const unsigned int*)h;

    int start = 0, end = 0;
    if (g < G) {
        int lo = 0, hi = n;
        while (lo < hi) { int mid = (lo + hi) >> 1; if (batch[mid] < g) lo = mid + 1; else hi = mid; }
        start = lo;
        hi = n;
        while (lo < hi) { int mid = (lo + hi) >> 1; if (batch[mid] < g + 1) lo = mid + 1; else hi = mid; }
        end = lo;
    }

    float a0 = 0.f, a1 = 0.f, a2 = 0.f, a3 = 0.f;
    int nb = start;
    for (; nb + 4 <= end; nb += 4) {
        int node = nb + grp;
        uint2 v = *(const uint2*)&h32[(size_t)node * 32 + t * 2];
        a0 += bflo(v.x); a1 += bfhi(v.x); a2 += bflo(v.y); a3 += bfhi(v.y);
    }
    if (grp < end - nb) {
        int node = nb + grp;
        uint2 v = *(const uint2*)&h32[(size_t)node * 32 + t * 2];
        a0 += bflo(v.x); a1 += bfhi(v.x); a2 += bflo(v.y); a3 += bfhi(v.y);
    }
    a0 += __shfl_xor(a0, 16, 64); a1 += __shfl_xor(a1, 16, 64);
    a2 += __shfl_xor(a2, 16, 64); a3 += __shfl_xor(a3, 16, 64);
    a0 += __shfl_xor(a0, 32, 64); a1 += __shfl_xor(a1, 32, 64);
    a2 += __shfl_xor(a2, 32, 64); a3 += __shfl_xor(a3, 32, 64);

    float cnt = (float)((end - start) > 0 ? (end - start) : 1);
    if (grp == 0) {
        gsm[wv][t * 4 + 0] = a0 / cnt;
        gsm[wv][t * 4 + 1] = a1 / cnt;
        gsm[wv][t * 4 + 2] = a2 / cnt;
        gsm[wv][t * 4 + 3] = a3 / cnt;
    }
    __syncthreads();
    if (g < G) {
        float pj = l1b[lane];
#pragma unroll
        for (int k = 0; k < 64; k++) pj = fmaf(gsm[wv][k], wl[lane * 65 + k], pj);
        pj = fmaxf(pj, 0.f);
        for (int o = 0; o < 3; o++) {
            float v = pj * l2w[o * 64 + lane];
            for (int off = 32; off; off >>= 1) v += __shfl_xor(v, off, 64);
            if (lane == 0) out[g * 3 + o] = v + l2b[o];
        }
    }
}

// ---------------- launch ----------------

extern "C" void kernel_launch(void* const* d_in, const int* in_sizes, int n_in,
                              void* d_out, int out_size, void* d_ws, size_t ws_size,
                              hipStream_t stream) {
    const float* x      = (const float*)d_in[0];
    const int*   edge   = (const int*)d_in[1];
    const int*   batch  = (const int*)d_in[2];
    const float* emb_w  = (const float*)d_in[3];
    const float* emb_b  = (const float*)d_in[4];
    const float* conv_w = (const float*)d_in[5];
    const float* conv_b = (const float*)d_in[6];
    const float* l1w    = (const float*)d_in[7];
    const float* l1b    = (const float*)d_in[8];
    const float* l2w    = (const float*)d_in[9];
    const float* l2b    = (const float*)d_in[10];
    float* out = (float*)d_out;

    const int N = in_sizes[2];      // 100000 nodes
    const int E = in_sizes[1] / 2;  // 3200000 edges
    const int G = out_size / 3;     // 2000 graphs
    const int NB = (N + 127) >> 7;  // bins of 128 nodes (782)

    char* ws = (char*)d_ws;
    size_t off = 0;
    auto alloc = [&](size_t bytes) -> void* {
        void* p = ws + off;
        off = (off + bytes + 255) & ~(size_t)255;
        return p;
    };
    float* dinv     = (float*)alloc((size_t)N * 4);
    int*   bincntP  = (int*)alloc((size_t)NB * 4);
    int*   bincntE  = (int*)alloc((size_t)NB * 4);
    int*   binstart = (int*)alloc((size_t)NB * 4);
    int*   colw     = (int*)alloc((size_t)E * 4);
    int*   rowptrS  = (int*)alloc(((size_t)NB * 1024 + 8) * 4);  // 3.2 MB
    int*   binbuf   = (int*)alloc((size_t)NB * BIN_CAP * 4);     // 25.6 MB
    // ubuf/hbuf alias binbuf (dead after k_binC):
    //   ubuf = binbuf[0 .. 12.8MB), first written by k_gemm0
    //   hbuf = binbuf[12.8MB .. 25.6MB), first written by first k_agg
    unsigned short* ubuf = (unsigned short*)binbuf;
    unsigned short* hbuf = (unsigned short*)((char*)binbuf + (size_t)N * 64 * 2);

    const int* esrc = edge;
    const int* edst = edge + E;

    // bincntP and bincntE are adjacent in ws -> one memset covers both
    hipMemsetAsync(bincntP, 0, (size_t)((char*)bincntE - (char*)bincntP) + (size_t)NB * 4, stream);
    k_binA<<<256, 1024, 0, stream>>>(esrc, edst, bincntP, bincntE, binbuf, E, NB);
    k_scanB<<<1, 1024, 0, stream>>>(bincntE, binstart, NB);
    k_binC<<<NB, 1024, 0, stream>>>(bincntP, binstart, binbuf, dinv, rowptrS, colw, N);

    int aggBlocks = (N + NPB - 1) / NPB;  // 2084 -> ~8 blocks/CU, ~full occupancy
    k_gemm0<<<(N + 63) / 64, 256, 0, stream>>>(x, emb_w, emb_b, conv_w, dinv, ubuf, N);
    k_agg<<<aggBlocks, 256, 0, stream>>>(ubuf, rowptrS, colw, dinv, conv_b, hbuf, N);
    for (int l = 1; l < 3; l++) {
        k_gemm<<<(N + 63) / 64, 256, 0, stream>>>(hbuf, conv_w + (size_t)l * 64 * 64, dinv, ubuf, N);
        k_agg<<<aggBlocks, 256, 0, stream>>>(ubuf, rowptrS, colw, dinv,
                                             conv_b + (size_t)l * 64, hbuf, N);
    }

    k_pool<<<(G + 3) / 4, 256, 0, stream>>>(hbuf, batch, l1w, l1b, l2w, l2b, out, N, G);
}

// Round 16
// 449.096 us; speedup vs baseline: 1.1585x; 1.0529x over previous
//
#include <hip/hip_runtime.h>

// ---------------- bf16 helpers ----------------
__device__ __forceinline__ unsigned short f2bf(float f) {
    union { float f; unsigned int u; } c; c.f = f;
    unsigned int r = c.u + 0x7fffu + ((c.u >> 16) & 1u);  // RTNE
    return (unsigned short)(r >> 16);
}
__device__ __forceinline__ float bflo(unsigned int v) {
    union { unsigned int u; float f; } c; c.u = v << 16; return c.f;
}
__device__ __forceinline__ float bfhi(unsigned int v) {
    union { unsigned int u; float f; } c; c.u = v & 0xffff0000u; return c.f;
}

// ---------------- CSR build ----------------
// Bins of 128 nodes by dst. Records pack (dst&127)<<20 | src (src < 2^20).
// k_binA: 256 blocks x 1024 threads, chunked two-phase; per-(block,bin) spans
// padded to 16 records (64B single-writer lines). Sentinel 0x7FFFFFFF
// (src-field >= N) skipped downstream.

#define BIN_CAP 10240
#define NBINS_MAX 1024  // N=100000 -> 782 bins

__global__ __launch_bounds__(1024) void k_binA(const int* __restrict__ src,
                                               const int* __restrict__ dst,
                                               int* __restrict__ bincntPad,
                                               int* __restrict__ bincntExact,
                                               int* __restrict__ binbuf,
                                               int E, int nbins) {
    __shared__ int hist[NBINS_MAX];
    __shared__ int lbase[NBINS_MAX];
    int tid = threadIdx.x;
    int chunk = (E + gridDim.x - 1) / gridDim.x;
    int e0 = blockIdx.x * chunk;
    int e1 = min(e0 + chunk, E);

    for (int i = tid; i < nbins; i += 1024) hist[i] = 0;
    __syncthreads();
    for (int e = e0 + tid; e < e1; e += 1024) atomicAdd(&hist[dst[e] >> 7], 1);
    __syncthreads();
    for (int i = tid; i < nbins; i += 1024) {
        int c = hist[i];
        if (c) {
            atomicAdd(&bincntExact[i], c);
            lbase[i] = atomicAdd(&bincntPad[i], (c + 15) & ~15);
        }
        hist[i] = 0;  // reuse as cursor
    }
    __syncthreads();
    for (int e = e0 + tid; e < e1; e += 1024) {
        int d = dst[e], s = src[e];
        int b = d >> 7;
        int pos = lbase[b] + atomicAdd(&hist[b], 1);
        binbuf[(size_t)b * BIN_CAP + pos] = ((d & 127) << 20) | s;
    }
    __syncthreads();
    // sentinel-pad each span tail to the 16-record boundary
    for (int i = tid; i < nbins; i += 1024) {
        int c = hist[i];
        if (c & 15) {
            int* p = binbuf + (size_t)i * BIN_CAP + lbase[i] + c;
            int pad = 16 - (c & 15);
            for (int j = 0; j < pad; j++) p[j] = 0x7FFFFFFF;
        }
    }
}

// single-block exclusive scan of exact bin counts -> binstart (nbins <= 1024)
__global__ void k_scanB(const int* __restrict__ cntE, int* __restrict__ binstart,
                        int nbins) {
    __shared__ int s[1024];
    int tid = threadIdx.x;
    int v = (tid < nbins) ? cntE[tid] : 0;
    s[tid] = v;
    __syncthreads();
    for (int off = 1; off < 1024; off <<= 1) {
        int t = (tid >= off) ? s[tid - off] : 0;
        __syncthreads();
        s[tid] += t;
        __syncthreads();
    }
    if (tid < nbins) binstart[tid] = s[tid] - v;
}

// one block (512 thr) per bin: two int4 streaming passes over the bin's padded
// records (no LDS staging): pass1 histogram -> deg/dinv/rowptr; pass2 scatter
// col into the bin's contiguous exact window via LDS int cursors.
__global__ __launch_bounds__(512) void k_binC(const int* __restrict__ bincntPad,
                                              const int* __restrict__ binstart,
                                              const int* __restrict__ binbuf,
                                              int* __restrict__ deg,
                                              float* __restrict__ dinv,
                                              int* __restrict__ rowptr,
                                              int* __restrict__ col, int n) {
    __shared__ int hist[128];
    __shared__ int scn[128];
    __shared__ int cur[128];
    int b = blockIdx.x, tid = threadIdx.x;
    int cnt = bincntPad[b];  // multiple of 16
    const int* rec = binbuf + (size_t)b * BIN_CAP;
    if (tid < 128) hist[tid] = 0;
    __syncthreads();
    for (int i = tid * 4; i + 3 < cnt; i += 2048) {
        int4 r4 = *(const int4*)&rec[i];
        if ((r4.x & 0xFFFFF) < n) atomicAdd(&hist[(r4.x >> 20) & 127], 1);
        if ((r4.y & 0xFFFFF) < n) atomicAdd(&hist[(r4.y >> 20) & 127], 1);
        if ((r4.z & 0xFFFFF) < n) atomicAdd(&hist[(r4.z >> 20) & 127], 1);
        if ((r4.w & 0xFFFFF) < n) atomicAdd(&hist[(r4.w >> 20) & 127], 1);
    }
    __syncthreads();
    int v = (tid < 128) ? hist[tid] : 0;
    if (tid < 128) scn[tid] = v;
    __syncthreads();
    for (int off = 1; off < 128; off <<= 1) {
        int t = (tid < 128 && tid >= off) ? scn[tid - off] : 0;
        __syncthreads();
        if (tid < 128) scn[tid] += t;
        __syncthreads();
    }
    int rowbase = binstart[b];
    if (tid < 128) {
        int excl = scn[tid] - v;
        cur[tid] = rowbase + excl;
        int node = b * 128 + tid;
        if (node < n) {
            deg[node] = v;
            dinv[node] = rsqrtf((float)(v + 1));  // +1 self loop
            rowptr[node] = rowbase + excl;
        }
    }
    __syncthreads();
    for (int i = tid * 4; i + 3 < cnt; i += 2048) {
        int4 r4 = *(const int4*)&rec[i];
        int s0 = r4.x & 0xFFFFF, s1 = r4.y & 0xFFFFF;
        int s2 = r4.z & 0xFFFFF, s3 = r4.w & 0xFFFFF;
        if (s0 < n) col[atomicAdd(&cur[(r4.x >> 20) & 127], 1)] = s0;
        if (s1 < n) col[atomicAdd(&cur[(r4.y >> 20) & 127], 1)] = s1;
        if (s2 < n) col[atomicAdd(&cur[(r4.z >> 20) & 127], 1)] = s2;
        if (s3 < n) col[atomicAdd(&cur[(r4.w >> 20) & 127], 1)] = s3;
    }
}

// ---------------- dense compute (h, u stored as bf16) ----------------

// layer-0 fused: h = x @ emb_w^T + emb_b computed in-LDS, then u = (h @ W^T)*dinv -> bf16
__global__ __launch_bounds__(256) void k_gemm0(const float* __restrict__ x,
                                               const float* __restrict__ embw,
                                               const float* __restrict__ embb,
                                               const float* __restrict__ W,
                                               const float* __restrict__ dinv,
                                               unsigned short* __restrict__ uout, int n) {
    __shared__ float hN[64 * 68];
    __shared__ float wT[64 * 68];
    __shared__ float sX[64 * 4];
    __shared__ float sW[64 * 4];
    __shared__ float sB[64];
    int tid = threadIdx.x;
    int nbase = blockIdx.x * 64;
    for (int i = tid; i < 4096; i += 256) {
        int j = i >> 6, k = i & 63;
        wT[k * 68 + j] = W[i];
    }
    if (tid < 256) sW[tid] = embw[tid];
    if (tid < 64) sB[tid] = embb[tid];
    {
        int node = nbase + (tid >> 2);
        sX[tid] = (node < n) ? x[(size_t)node * 4 + (tid & 3)] : 0.f;
    }
    __syncthreads();
    for (int i = tid; i < 4096; i += 256) {
        int nn = i >> 6, k = i & 63;
        float s = sB[k];
        s = fmaf(sX[nn * 4 + 0], sW[k * 4 + 0], s);
        s = fmaf(sX[nn * 4 + 1], sW[k * 4 + 1], s);
        s = fmaf(sX[nn * 4 + 2], sW[k * 4 + 2], s);
        s = fmaf(sX[nn * 4 + 3], sW[k * 4 + 3], s);
        hN[nn * 68 + k] = s;
    }
    __syncthreads();

    int tx = tid & 15;
    int ty = tid >> 4;
    float acc[4][4] = {};
#pragma unroll
    for (int k0 = 0; k0 < 64; k0 += 4) {
        float a[4][4], w[4][4];
#pragma unroll
        for (int i = 0; i < 4; i++)
            *(float4*)a[i] = *(const float4*)&hN[(ty * 4 + i) * 68 + k0];
#pragma unroll
        for (int dk = 0; dk < 4; dk++)
            *(float4*)w[dk] = *(const float4*)&wT[(k0 + dk) * 68 + tx * 4];
#pragma unroll
        for (int i = 0; i < 4; i++)
#pragma unroll
            for (int j = 0; j < 4; j++)
#pragma unroll
                for (int dk = 0; dk < 4; dk++)
                    acc[i][j] = fmaf(a[i][dk], w[dk][j], acc[i][j]);
    }
#pragma unroll
    for (int i = 0; i < 4; i++) {
        int node = nbase + ty * 4 + i;
        if (node < n) {
            float sc = dinv[node];
            ushort4 o;
            o.x = f2bf(acc[i][0] * sc);
            o.y = f2bf(acc[i][1] * sc);
            o.z = f2bf(acc[i][2] * sc);
            o.w = f2bf(acc[i][3] * sc);
            *(ushort4*)&uout[(size_t)node * 64 + tx * 4] = o;
        }
    }
}

// u = (h @ W^T) * dinv[node]; h bf16 in, u bf16 out
__global__ __launch_bounds__(256) void k_gemm(const unsigned short* __restrict__ hin,
                                              const float* __restrict__ W,
                                              const float* __restrict__ dinv,
                                              unsigned short* __restrict__ uout, int n) {
    __shared__ float hN[64 * 68];
    __shared__ float wT[64 * 68];
    int tid = threadIdx.x;
    int nbase = blockIdx.x * 64;
    for (int i = tid; i < 4096; i += 256) {
        int j = i >> 6, k = i & 63;
        wT[k * 68 + j] = W[i];
    }
    for (int i = tid; i < 2048; i += 256) {
        int nn = i >> 5, k2 = i & 31;
        int node = nbase + nn;
        unsigned int v = (node < n) ? ((const unsigned int*)hin)[(size_t)node * 32 + k2] : 0u;
        hN[nn * 68 + k2 * 2 + 0] = bflo(v);
        hN[nn * 68 + k2 * 2 + 1] = bfhi(v);
    }
    __syncthreads();

    int tx = tid & 15;
    int ty = tid >> 4;
    float acc[4][4] = {};
#pragma unroll
    for (int k0 = 0; k0 < 64; k0 += 4) {
        float a[4][4], w[4][4];
#pragma unroll
        for (int i = 0; i < 4; i++)
            *(float4*)a[i] = *(const float4*)&hN[(ty * 4 + i) * 68 + k0];
#pragma unroll
        for (int dk = 0; dk < 4; dk++)
            *(float4*)w[dk] = *(const float4*)&wT[(k0 + dk) * 68 + tx * 4];
#pragma unroll
        for (int i = 0; i < 4; i++)
#pragma unroll
            for (int j = 0; j < 4; j++)
#pragma unroll
                for (int dk = 0; dk < 4; dk++)
                    acc[i][j] = fmaf(a[i][dk], w[dk][j], acc[i][j]);
    }
#pragma unroll
    for (int i = 0; i < 4; i++) {
        int node = nbase + ty * 4 + i;
        if (node < n) {
            float sc = dinv[node];
            ushort4 o;
            o.x = f2bf(acc[i][0] * sc);
            o.y = f2bf(acc[i][1] * sc);
            o.z = f2bf(acc[i][2] * sc);
            o.w = f2bf(acc[i][3] * sc);
            *(ushort4*)&uout[(size_t)node * 64 + tx * 4] = o;
        }
    }
}

// wave per node, 16-lane groups x uint2 (4 bf16): 4 edges per iteration, unroll 4.
// h[n] = relu(dinv[n] * (u[n] + sum_in u[s]) + bias)
__global__ void k_agg(const unsigned short* __restrict__ u, const int* __restrict__ rowptr,
                      const int* __restrict__ deg, const int* __restrict__ col,
                      const float* __restrict__ dinv, const float* __restrict__ bias,
                      unsigned short* __restrict__ hout, int n) {
    int wid = (blockIdx.x * blockDim.x + threadIdx.x) >> 6;
    int lane = threadIdx.x & 63;
    if (wid >= n) return;
    int g = lane >> 4, t = lane & 15;
    const unsigned int* u32 = (const unsigned int*)u;
    const int toff = t * 2;

    float a0 = 0.f, a1 = 0.f, a2 = 0.f, a3 = 0.f;
    if (g == 0) {  // self-loop term, counted once
        uint2 v = *(const uint2*)&u32[(size_t)wid * 32 + toff];
        a0 = bflo(v.x); a1 = bfhi(v.x); a2 = bflo(v.y); a3 = bfhi(v.y);
    }
    int p0 = rowptr[wid];
    int e = p0 + deg[wid];
    int p = p0 + g;
    for (; p + 12 < e; p += 16) {
        int s0 = col[p], s1 = col[p + 4], s2 = col[p + 8], s3 = col[p + 12];
        uint2 v0 = *(const uint2*)&u32[(size_t)s0 * 32 + toff];
        uint2 v1 = *(const uint2*)&u32[(size_t)s1 * 32 + toff];
        uint2 v2 = *(const uint2*)&u32[(size_t)s2 * 32 + toff];
        uint2 v3 = *(const uint2*)&u32[(size_t)s3 * 32 + toff];
        a0 += bflo(v0.x); a1 += bfhi(v0.x); a2 += bflo(v0.y); a3 += bfhi(v0.y);
        a0 += bflo(v1.x); a1 += bfhi(v1.x); a2 += bflo(v1.y); a3 += bfhi(v1.y);
        a0 += bflo(v2.x); a1 += bfhi(v2.x); a2 += bflo(v2.y); a3 += bfhi(v2.y);
        a0 += bflo(v3.x); a1 += bfhi(v3.x); a2 += bflo(v3.y); a3 += bfhi(v3.y);
    }
    for (; p < e; p += 4) {
        int s0 = col[p];
        uint2 v0 = *(const uint2*)&u32[(size_t)s0 * 32 + toff];
        a0 += bflo(v0.x); a1 += bfhi(v0.x); a2 += bflo(v0.y); a3 += bfhi(v0.y);
    }
    // reduce across the 4 groups
    a0 += __shfl_xor(a0, 16, 64); a1 += __shfl_xor(a1, 16, 64);
    a2 += __shfl_xor(a2, 16, 64); a3 += __shfl_xor(a3, 16, 64);
    a0 += __shfl_xor(a0, 32, 64); a1 += __shfl_xor(a1, 32, 64);
    a2 += __shfl_xor(a2, 32, 64); a3 += __shfl_xor(a3, 32, 64);

    if (g == 0) {
        float sc = dinv[wid];
        float f0 = fmaxf(fmaf(sc, a0, bias[t * 4 + 0]), 0.f);
        float f1 = fmaxf(fmaf(sc, a1, bias[t * 4 + 1]), 0.f);
        float f2 = fmaxf(fmaf(sc, a2, bias[t * 4 + 2]), 0.f);
        float f3 = fmaxf(fmaf(sc, a3, bias[t * 4 + 3]), 0.f);
        ushort4 o;
        o.x = f2bf(f0); o.y = f2bf(f1); o.z = f2bf(f2); o.w = f2bf(f3);
        *(ushort4*)&hout[(size_t)wid * 64 + t * 4] = o;
    }
}

// one wave per graph: mean pool (contiguous rows, 16-lane groups x uint2) + MLP head
__global__ __launch_bounds__(256) void k_pool(const unsigned short* __restrict__ h,
                                              const int* __restrict__ batch,
                                              const float* __restrict__ l1w,
                                              const float* __restrict__ l1b,
                                              const float* __restrict__ l2w,
                                              const float* __restrict__ l2b,
                                              float* __restrict__ out, int n, int G) {
    __shared__ float wl[64 * 65];
    __shared__ float gsm[4][64];
    int tid = threadIdx.x;
    for (int i = tid; i < 4096; i += 256) {
        int j = i >> 6, k = i & 63;
        wl[j * 65 + k] = l1w[i];
    }
    int wv = tid >> 6;
    int lane = tid & 63;
    int g = blockIdx.x * 4 + wv;
    int grp = lane >> 4, t = lane & 15;
    const unsigned int* h32 = (const unsigned int*)h;

    int start = 0, end = 0;
    if (g < G) {
        int lo = 0, hi = n;
        while (lo < hi) { int mid = (lo + hi) >> 1; if (batch[mid] < g) lo = mid + 1; else hi = mid; }
        start = lo;
        hi = n;
        while (lo < hi) { int mid = (lo + hi) >> 1; if (batch[mid] < g + 1) lo = mid + 1; else hi = mid; }
        end = lo;
    }

    float a0 = 0.f, a1 = 0.f, a2 = 0.f, a3 = 0.f;
    int nb = start;
    for (; nb + 4 <= end; nb += 4) {
        int node = nb + grp;
        uint2 v = *(const uint2*)&h32[(size_t)node * 32 + t * 2];
        a0 += bflo(v.x); a1 += bfhi(v.x); a2 += bflo(v.y); a3 += bfhi(v.y);
    }
    if (grp < end - nb) {
        int node = nb + grp;
        uint2 v = *(const uint2*)&h32[(size_t)node * 32 + t * 2];
        a0 += bflo(v.x); a1 += bfhi(v.x); a2 += bflo(v.y); a3 += bfhi(v.y);
    }
    a0 += __shfl_xor(a0, 16, 64); a1 += __shfl_xor(a1, 16, 64);
    a2 += __shfl_xor(a2, 16, 64); a3 += __shfl_xor(a3, 16, 64);
    a0 += __shfl_xor(a0, 32, 64); a1 += __shfl_xor(a1, 32, 64);
    a2 += __shfl_xor(a2, 32, 64); a3 += __shfl_xor(a3, 32, 64);

    float cnt = (float)((end - start) > 0 ? (end - start) : 1);
    if (grp == 0) {
        gsm[wv][t * 4 + 0] = a0 / cnt;
        gsm[wv][t * 4 + 1] = a1 / cnt;
        gsm[wv][t * 4 + 2] = a2 / cnt;
        gsm[wv][t * 4 + 3] = a3 / cnt;
    }
    __syncthreads();
    if (g < G) {
        float pj = l1b[lane];
#pragma unroll
        for (int k = 0; k < 64; k++) pj = fmaf(gsm[wv][k], wl[lane * 65 + k], pj);
        pj = fmaxf(pj, 0.f);
        for (int o = 0; o < 3; o++) {
            float v = pj * l2w[o * 64 + lane];
            for (int off = 32; off; off >>= 1) v += __shfl_xor(v, off, 64);
            if (lane == 0) out[g * 3 + o] = v + l2b[o];
        }
    }
}

// ---------------- launch ----------------

extern "C" void kernel_launch(void* const* d_in, const int* in_sizes, int n_in,
                              void* d_out, int out_size, void* d_ws, size_t ws_size,
                              hipStream_t stream) {
    const float* x      = (const float*)d_in[0];
    const int*   edge   = (const int*)d_in[1];
    const int*   batch  = (const int*)d_in[2];
    const float* emb_w  = (const float*)d_in[3];
    const float* emb_b  = (const float*)d_in[4];
    const float* conv_w = (const float*)d_in[5];
    const float* conv_b = (const float*)d_in[6];
    const float* l1w    = (const float*)d_in[7];
    const float* l1b    = (const float*)d_in[8];
    const float* l2w    = (const float*)d_in[9];
    const float* l2b    = (const float*)d_in[10];
    float* out = (float*)d_out;

    const int N = in_sizes[2];      // 100000 nodes
    const int E = in_sizes[1] / 2;  // 3200000 edges
    const int G = out_size / 3;     // 2000 graphs
    const int NB = (N + 127) >> 7;  // bins of 128 nodes (782)

    char* ws = (char*)d_ws;
    size_t off = 0;
    auto alloc = [&](size_t bytes) -> void* {
        void* p = ws + off;
        off = (off + bytes + 255) & ~(size_t)255;
        return p;
    };
    int*   deg      = (int*)alloc((size_t)N * 4);
    float* dinv     = (float*)alloc((size_t)N * 4);
    int*   rowptr   = (int*)alloc((size_t)N * 4);
    int*   bincntP  = (int*)alloc((size_t)NB * 4);
    int*   bincntE  = (int*)alloc((size_t)NB * 4);
    int*   binstart = (int*)alloc((size_t)NB * 4);
    int*   colw     = (int*)alloc((size_t)E * 4);
    int*   binbuf   = (int*)alloc((size_t)NB * BIN_CAP * 4);  // 32 MB
    // ubuf/hbuf alias binbuf (dead after k_binC):
    //   ubuf = binbuf[0 .. 12.8MB), first written by k_gemm0
    //   hbuf = binbuf[12.8MB .. 25.6MB), first written by first k_agg
    unsigned short* ubuf = (unsigned short*)binbuf;
    unsigned short* hbuf = (unsigned short*)((char*)binbuf + (size_t)N * 64 * 2);

    const int* esrc = edge;
    const int* edst = edge + E;

    // bincntP and bincntE are adjacent in ws -> one memset covers both
    hipMemsetAsync(bincntP, 0, (size_t)((char*)bincntE - (char*)bincntP) + (size_t)NB * 4, stream);
    k_binA<<<256, 1024, 0, stream>>>(esrc, edst, bincntP, bincntE, binbuf, E, NB);
    k_scanB<<<1, 1024, 0, stream>>>(bincntE, binstart, NB);
    k_binC<<<NB, 512, 0, stream>>>(bincntP, binstart, binbuf, deg, dinv, rowptr, colw, N);

    k_gemm0<<<(N + 63) / 64, 256, 0, stream>>>(x, emb_w, emb_b, conv_w, dinv, ubuf, N);
    k_agg<<<(N + 3) / 4, 256, 0, stream>>>(ubuf, rowptr, deg, colw, dinv, conv_b, hbuf, N);
    for (int l = 1; l < 3; l++) {
        k_gemm<<<(N + 63) / 64, 256, 0, stream>>>(hbuf, conv_w + (size_t)l * 64 * 64, dinv, ubuf, N);
        k_agg<<<(N + 3) / 4, 256, 0, stream>>>(ubuf, rowptr, deg, colw, dinv, conv_b + (size_t)l * 64, hbuf, N);
    }

    k_pool<<<(G + 3) / 4, 256, 0, stream>>>(hbuf, batch, l1w, l1b, l2w, l2b, out, N, G);
}